// Round 3
// baseline (8924.815 us; speedup 1.0000x reference)
//
#include <hip/hip_runtime.h>

// Problem constants (from reference setup_inputs)
#define N_NODES 100001
#define DT 0.1f
#define N_STEPS 100

// Blocked layout: 64 row-groups x 8 col-blocks = 512 segments
#define GRPS 64
#define GR   1568            // rows per group (64*1568 = 100352 >= 100001), < 2048 (11 bits)
#define BLKS 8
#define BC   12544           // cols per block (8*12544 = 100352), < 16384 (14 bits)
#define NSEG (GRPS * BLKS)
#define NPAD (GRPS * GR)     // 100352

// ---------------------------------------------------------------------------
// Blocked-CSR build: histogram over 512 segments, scan, bucketed scatter
// ---------------------------------------------------------------------------

__global__ void seg_hist_kernel(const int* __restrict__ rows,
                                const int* __restrict__ cols,
                                int* __restrict__ seg_cnt, int E) {
    int e = blockIdx.x * blockDim.x + threadIdx.x;
    if (e >= E) return;
    int seg = (rows[e] / GR) * BLKS + (cols[e] / BC);
    atomicAdd(&seg_cnt[seg], 1);
}

__global__ __launch_bounds__(512) void seg_scan_kernel(const int* __restrict__ seg_cnt,
                                                       int* __restrict__ seg_base) {
    __shared__ int tmp[NSEG];
    int tid = threadIdx.x;
    tmp[tid] = seg_cnt[tid];
    __syncthreads();
    for (int d = 1; d < NSEG; d <<= 1) {
        int v = (tid >= d) ? tmp[tid - d] : 0;
        __syncthreads();
        tmp[tid] += v;
        __syncthreads();
    }
    seg_base[tid] = tmp[tid] - seg_cnt[tid];   // exclusive
    if (tid == NSEG - 1) seg_base[NSEG] = tmp[tid];
}

// Scatter edges to their segment (order within a segment is irrelevant).
// meta = (localrow << 14) | localcol ; val masked per reference row-0 rules.
__global__ void seg_fill_kernel(const int* __restrict__ rows,
                                const int* __restrict__ cols,
                                const float* __restrict__ pol,
                                const int* __restrict__ seg_base,
                                int* __restrict__ cursor,
                                uint2* __restrict__ edges, int E) {
    int e = blockIdx.x * blockDim.x + threadIdx.x;
    if (e >= E) return;
    int r = rows[e];
    int c = cols[e];
    int g = r / GR;
    int b = c / BC;
    float v = (r == 0) ? ((c == 0) ? 1.0f : 0.0f) : DT * pol[e];
    unsigned meta = ((unsigned)(r - g * GR) << 14) | (unsigned)(c - b * BC);
    int pos = seg_base[g * BLKS + b] + atomicAdd(&cursor[g * BLKS + b], 1);
    edges[pos] = make_uint2(meta, __float_as_uint(v));
}

// ---------------------------------------------------------------------------
// Iteration kernels
// ---------------------------------------------------------------------------

__global__ void init_x_kernel(float* __restrict__ x, int n) {
    int i = blockIdx.x * blockDim.x + threadIdx.x;
    if (i < n) x[i] = 1.0f;
}

// One WG per (group, block) segment. Stage x-slice in LDS, gather from LDS,
// accumulate per-row partials via LDS float atomics, write partials.
__global__ __launch_bounds__(256) void spmv_blocked_kernel(const uint2* __restrict__ edges,
                                                           const int* __restrict__ seg_base,
                                                           const float* __restrict__ x,
                                                           float* __restrict__ partials) {
    __shared__ float lds_x[BC];
    __shared__ float lds_y[GR];
    const int wg = blockIdx.x;
    const int g = wg >> 3;          // row group
    const int b = wg & 7;           // col block
    const int tid = threadIdx.x;
    const int cbase = b * BC;

    // Stage x slice (coalesced float4 where safe; last block crosses N)
    if (cbase + BC <= N_NODES) {
        const float4* xv = (const float4*)(x + cbase);
        for (int j = tid; j < BC / 4; j += 256) {
            float4 t = xv[j];
            lds_x[4 * j + 0] = t.x; lds_x[4 * j + 1] = t.y;
            lds_x[4 * j + 2] = t.z; lds_x[4 * j + 3] = t.w;
        }
    } else {
        for (int j = tid; j < BC; j += 256) {
            int gi = cbase + j;
            lds_x[j] = (gi < N_NODES) ? x[gi] : 0.0f;
        }
    }
    for (int r = tid; r < GR; r += 256) lds_y[r] = 0.0f;
    __syncthreads();

    // Process this segment's edges
    const int s = seg_base[wg];
    const int e = seg_base[wg + 1];
    for (int i = s + tid; i < e; i += 256) {
        uint2 ed = edges[i];
        int lc = ed.x & 16383;
        int lr = ed.x >> 14;
        float v = __uint_as_float(ed.y);
        atomicAdd(&lds_y[lr], v * lds_x[lc]);
    }
    __syncthreads();

    // Write this block's partial for the group's rows (coalesced, no init needed)
    float* p = partials + (size_t)b * NPAD + (size_t)g * GR;
    for (int r = tid; r < GR; r += 256) p[r] = lds_y[r];
}

// x_next[i] = diag_i * x[i] + sum_b partials[b][i]
__global__ void combine_kernel(const float* __restrict__ x,
                               const float* __restrict__ partials,
                               float* __restrict__ xn, int n) {
    int i = blockIdx.x * blockDim.x + threadIdx.x;
    if (i >= n) return;
    float acc = ((i == 0) ? 1.0f : (1.0f - DT)) * x[i];
    #pragma unroll
    for (int b = 0; b < BLKS; ++b) acc += partials[(size_t)b * NPAD + i];
    xn[i] = acc;
}

// ---------------------------------------------------------------------------
// Fallback path kernels (round-2: wave-per-row CSR; COO)
// ---------------------------------------------------------------------------

__global__ void hist_kernel(const int* __restrict__ rows,
                            int* __restrict__ counts, int E) {
    int e = blockIdx.x * blockDim.x + threadIdx.x;
    if (e < E) atomicAdd(&counts[rows[e]], 1);
}

__global__ __launch_bounds__(1024) void scan_kernel(const int* __restrict__ counts,
                                                    int* __restrict__ row_ptr, int n) {
    __shared__ int tmp[1024];
    int tid = threadIdx.x;
    int per = (n + 1023) >> 10;
    int start = tid * per;
    int end = min(start + per, n);
    int sum = 0;
    for (int i = start; i < end; ++i) sum += counts[i];
    tmp[tid] = sum;
    __syncthreads();
    for (int d = 1; d < 1024; d <<= 1) {
        int v = (tid >= d) ? tmp[tid - d] : 0;
        __syncthreads();
        tmp[tid] += v;
        __syncthreads();
    }
    int off = tmp[tid] - sum;
    for (int i = start; i < end; ++i) { row_ptr[i] = off; off += counts[i]; }
    if (tid == 1023) row_ptr[n] = tmp[1023];
}

__global__ void fill_kernel(const int* __restrict__ rows,
                            const int* __restrict__ cols,
                            const float* __restrict__ pol,
                            const int* __restrict__ row_ptr,
                            int* __restrict__ cursor,
                            int* __restrict__ csr_col,
                            float* __restrict__ csr_val, int E) {
    int e = blockIdx.x * blockDim.x + threadIdx.x;
    if (e >= E) return;
    int r = rows[e];
    int c = cols[e];
    float v = (r == 0) ? ((c == 0) ? 1.0f : 0.0f) : DT * pol[e];
    int pos = row_ptr[r] + atomicAdd(&cursor[r], 1);
    csr_col[pos] = c;
    csr_val[pos] = v;
}

__global__ __launch_bounds__(256) void spmv_kernel(const int* __restrict__ row_ptr,
                                                   const int* __restrict__ csr_col,
                                                   const float* __restrict__ csr_val,
                                                   const float* __restrict__ x,
                                                   float* __restrict__ y, int n) {
    int wave = (blockIdx.x * blockDim.x + threadIdx.x) >> 6;
    int lane = threadIdx.x & 63;
    if (wave >= n) return;
    int s = row_ptr[wave];
    int e = row_ptr[wave + 1];
    float acc = 0.0f;
    for (int i = s + lane; i < e; i += 64)
        acc += csr_val[i] * x[csr_col[i]];
    #pragma unroll
    for (int off = 32; off > 0; off >>= 1)
        acc += __shfl_down(acc, off, 64);
    if (lane == 0) {
        float diag = (wave == 0) ? 1.0f : (1.0f - DT);
        y[wave] = diag * x[wave] + acc;
    }
}

__global__ void coo_init_kernel(const float* __restrict__ x,
                                float* __restrict__ y, int n) {
    int i = blockIdx.x * blockDim.x + threadIdx.x;
    if (i < n) y[i] = ((i == 0) ? 1.0f : (1.0f - DT)) * x[i];
}

__global__ void coo_edge_kernel(const int* __restrict__ rows,
                                const int* __restrict__ cols,
                                const float* __restrict__ pol,
                                const float* __restrict__ x,
                                float* __restrict__ y, int E) {
    int e = blockIdx.x * blockDim.x + threadIdx.x;
    if (e >= E) return;
    int r = rows[e];
    int c = cols[e];
    float v = (r == 0) ? ((c == 0) ? 1.0f : 0.0f) : DT * pol[e];
    if (v != 0.0f) atomicAdd(&y[r], v * x[c]);
}

// ---------------------------------------------------------------------------
// Epilogue: max|x[1:]| then normalize
// ---------------------------------------------------------------------------

__global__ void max_kernel(const float* __restrict__ x, unsigned* __restrict__ maxbits, int n) {
    float m = 0.0f;
    for (int i = 1 + blockIdx.x * blockDim.x + threadIdx.x; i < n; i += gridDim.x * blockDim.x)
        m = fmaxf(m, fabsf(x[i]));
    #pragma unroll
    for (int off = 32; off > 0; off >>= 1)
        m = fmaxf(m, __shfl_down(m, off, 64));
    __shared__ float smax[4];
    int lane = threadIdx.x & 63, w = threadIdx.x >> 6;
    if (lane == 0) smax[w] = m;
    __syncthreads();
    if (threadIdx.x == 0) {
        float mm = smax[0];
        for (int i = 1; i < (int)(blockDim.x >> 6); ++i) mm = fmaxf(mm, smax[i]);
        // spins non-negative -> uint compare == float compare
        atomicMax(maxbits, __float_as_uint(mm));
    }
}

__global__ void normalize_kernel(const float* __restrict__ x,
                                 const unsigned* __restrict__ maxbits,
                                 float* __restrict__ out, int n) {
    int i = blockIdx.x * blockDim.x + threadIdx.x;
    if (i >= n) return;
    if (i == 0) { out[0] = 1.0f; return; }
    float mv = __uint_as_float(*maxbits);
    out[i] = x[i] / mv;
}

// ---------------------------------------------------------------------------
// Launch
// ---------------------------------------------------------------------------

static inline size_t align_up(size_t v, size_t a) { return (v + a - 1) & ~(a - 1); }

extern "C" void kernel_launch(void* const* d_in, const int* in_sizes, int n_in,
                              void* d_out, int out_size, void* d_ws, size_t ws_size,
                              hipStream_t stream) {
    // Integer inputs arrive as int32 (harness convention). adj_ind is (2,E) flat.
    const int* adj   = (const int*)d_in[0];
    const float* pol = (const float*)d_in[1];
    const int E = in_sizes[1];
    const int N = N_NODES;
    const int* rows = adj;
    const int* cols = adj + E;

    const int TB = 256;
    const int eb = (E + TB - 1) / TB;
    const int nb = (N + TB - 1) / TB;

    // ---- Blocked-path workspace ----
    const size_t sz_segbase = align_up(sizeof(int) * (NSEG + 1), 256);
    const size_t sz_segcnt  = align_up(sizeof(int) * NSEG, 256);
    const size_t sz_cursor  = align_up(sizeof(int) * NSEG, 256);
    const size_t sz_edges   = align_up(sizeof(uint2) * (size_t)E, 256);
    const size_t sz_part    = align_up(sizeof(float) * (size_t)BLKS * NPAD, 256);
    const size_t sz_xp      = align_up(sizeof(float) * (size_t)NPAD, 256);
    const size_t need_blk   = sz_segbase + sz_segcnt + sz_cursor + sz_edges +
                              sz_part + 2 * sz_xp + 256;

    // ---- Round-2 CSR path workspace ----
    const size_t sz_rowptr = align_up(sizeof(int) * (size_t)(N + 1), 256);
    const size_t sz_counts = align_up(sizeof(int) * (size_t)N, 256);
    const size_t sz_col    = align_up(sizeof(int) * (size_t)E, 256);
    const size_t sz_val    = align_up(sizeof(float) * (size_t)E, 256);
    const size_t sz_x      = align_up(sizeof(float) * (size_t)N, 256);
    const size_t need_csr  = sz_rowptr + sz_counts + sz_col + sz_val + 2 * sz_x + 256;

    if (ws_size >= need_blk) {
        // ---------------- Blocked LDS-gather path ----------------
        char* p = (char*)d_ws;
        int* seg_base  = (int*)p;    p += sz_segbase;
        int* seg_cnt   = (int*)p;    p += sz_segcnt;
        int* cursor    = (int*)p;    p += sz_cursor;
        uint2* edges   = (uint2*)p;  p += sz_edges;
        float* parts   = (float*)p;  p += sz_part;
        float* x0      = (float*)p;  p += sz_xp;
        float* x1      = (float*)p;  p += sz_xp;
        unsigned* maxb = (unsigned*)p;

        hipMemsetAsync(seg_cnt, 0, sizeof(int) * NSEG, stream);
        hipMemsetAsync(cursor, 0, sizeof(int) * NSEG, stream);
        seg_hist_kernel<<<eb, TB, 0, stream>>>(rows, cols, seg_cnt, E);
        seg_scan_kernel<<<1, NSEG, 0, stream>>>(seg_cnt, seg_base);
        seg_fill_kernel<<<eb, TB, 0, stream>>>(rows, cols, pol, seg_base, cursor,
                                               edges, E);

        init_x_kernel<<<nb, TB, 0, stream>>>(x0, N);
        float* xin = x0;
        float* xout = x1;
        for (int s = 0; s < N_STEPS; ++s) {
            spmv_blocked_kernel<<<NSEG, TB, 0, stream>>>(edges, seg_base, xin, parts);
            combine_kernel<<<nb, TB, 0, stream>>>(xin, parts, xout, N);
            float* t = xin; xin = xout; xout = t;
        }

        hipMemsetAsync(maxb, 0, sizeof(unsigned), stream);
        max_kernel<<<512, TB, 0, stream>>>(xin, maxb, N);
        normalize_kernel<<<nb, TB, 0, stream>>>(xin, maxb, (float*)d_out, N);
    } else if (ws_size >= need_csr) {
        // ---------------- Round-2 CSR path ----------------
        char* p = (char*)d_ws;
        int* row_ptr   = (int*)p;      p += sz_rowptr;
        int* counts    = (int*)p;      p += sz_counts;
        int* csr_col   = (int*)p;      p += sz_col;
        float* csr_val = (float*)p;    p += sz_val;
        float* x0      = (float*)p;    p += sz_x;
        float* x1      = (float*)p;    p += sz_x;
        unsigned* maxb = (unsigned*)p;

        hipMemsetAsync(counts, 0, sizeof(int) * (size_t)N, stream);
        hist_kernel<<<eb, TB, 0, stream>>>(rows, counts, E);
        scan_kernel<<<1, 1024, 0, stream>>>(counts, row_ptr, N);
        hipMemsetAsync(counts, 0, sizeof(int) * (size_t)N, stream);
        fill_kernel<<<eb, TB, 0, stream>>>(rows, cols, pol, row_ptr, counts,
                                           csr_col, csr_val, E);

        init_x_kernel<<<nb, TB, 0, stream>>>(x0, N);
        float* xin = x0;
        float* xout = x1;
        const int spmv_blocks = (N * 64 + TB - 1) / TB;
        for (int s = 0; s < N_STEPS; ++s) {
            spmv_kernel<<<spmv_blocks, TB, 0, stream>>>(row_ptr, csr_col, csr_val,
                                                        xin, xout, N);
            float* t = xin; xin = xout; xout = t;
        }

        hipMemsetAsync(maxb, 0, sizeof(unsigned), stream);
        max_kernel<<<512, TB, 0, stream>>>(xin, maxb, N);
        normalize_kernel<<<nb, TB, 0, stream>>>(xin, maxb, (float*)d_out, N);
    } else {
        // ---------------- COO fallback ----------------
        char* p = (char*)d_ws;
        float* x0      = (float*)p;    p += sz_x;
        float* x1      = (float*)p;    p += sz_x;
        unsigned* maxb = (unsigned*)p;

        init_x_kernel<<<nb, TB, 0, stream>>>(x0, N);
        float* xin = x0;
        float* xout = x1;
        for (int s = 0; s < N_STEPS; ++s) {
            coo_init_kernel<<<nb, TB, 0, stream>>>(xin, xout, N);
            coo_edge_kernel<<<eb, TB, 0, stream>>>(rows, cols, pol, xin, xout, E);
            float* t = xin; xin = xout; xout = t;
        }

        hipMemsetAsync(maxb, 0, sizeof(unsigned), stream);
        max_kernel<<<512, TB, 0, stream>>>(xin, maxb, N);
        normalize_kernel<<<nb, TB, 0, stream>>>(xin, maxb, (float*)d_out, N);
    }
}